// Round 4
// baseline (6517.916 us; speedup 1.0000x reference)
//
#include <hip/hip_runtime.h>
#include <hip/hip_bf16.h>
#include <cstdint>

typedef __hip_bfloat16 bf16;
typedef __hip_bfloat162 bf162;
typedef __bf16 bf16x8 __attribute__((ext_vector_type(8)));
typedef float f32x4 __attribute__((ext_vector_type(4)));

// ---------- dtype detection ----------
__global__ void detect_kernel(const unsigned short* __restrict__ xr, int* __restrict__ flag) {
  if (threadIdx.x == 0 && blockIdx.x == 0) {
    int pass = 0;
    for (int i = 0; i < 64; ++i) {
      unsigned short h = xr[2 * i];
      int e = (h >> 7) & 0xFF;
      if (e >= 110 && e <= 140) pass++;
    }
    *flag = (pass >= 32) ? 1 : 0;
  }
}

// ---------- batched weight conversion: 12 tensors in one launch ----------
struct CvtDesc {
  const void* src;
  void* dst;
  int n, fi, fo, mode;  // mode 1: transpose [fi][fo] -> bf16 [fo][fi]; mode 0: flat fp32
};
struct CvtAll { CvtDesc d[12]; };

__global__ void convert_all_kernel(CvtAll all, const int* __restrict__ flag) {
  CvtDesc dd = all.d[blockIdx.y];
  int isbf = *flag;
  for (int i = blockIdx.x * blockDim.x + threadIdx.x; i < dd.n; i += gridDim.x * blockDim.x) {
    float v = isbf ? __bfloat162float(((const bf16*)dd.src)[i]) : ((const float*)dd.src)[i];
    if (dd.mode) {
      int k = i / dd.fo, nn = i - k * dd.fo;
      ((__bf16*)dd.dst)[(size_t)nn * dd.fi + k] = (__bf16)v;
    } else {
      ((float*)dd.dst)[i] = v;
    }
  }
}

// ---------- graph preprocessing ----------

__global__ void count_kernel(const int* __restrict__ dst, int* __restrict__ deg, int E) {
  int i = blockIdx.x * blockDim.x + threadIdx.x;
  if (i < E) atomicAdd(&deg[dst[i]], 1);
}

__global__ void dinv_kernel(const int* __restrict__ deg, float* __restrict__ dinv, int n) {
  int i = blockIdx.x * blockDim.x + threadIdx.x;
  if (i < n) dinv[i] = rsqrtf((float)(deg[i] + 1));  // +1 self-loop
}

__global__ void scan_block_kernel(const int* __restrict__ counts, int* __restrict__ excl,
                                  int* __restrict__ bsum, int n) {
  __shared__ int sd[1024];
  int t = threadIdx.x;
  int i = blockIdx.x * 1024 + t;
  int v = (i < n) ? counts[i] : 0;
  sd[t] = v;
  __syncthreads();
  for (int off = 1; off < 1024; off <<= 1) {
    int x = (t >= off) ? sd[t - off] : 0;
    __syncthreads();
    sd[t] += x;
    __syncthreads();
  }
  if (i < n) excl[i] = sd[t] - v;
  if (t == 1023) bsum[blockIdx.x] = sd[1023];
}

__global__ void scan_sums_kernel(int* __restrict__ bsum, int nb, int* __restrict__ row_ptr, int n) {
  __shared__ int sd[1024];
  int t = threadIdx.x;
  int v = (t < nb) ? bsum[t] : 0;
  sd[t] = v;
  __syncthreads();
  for (int off = 1; off < 1024; off <<= 1) {
    int x = (t >= off) ? sd[t - off] : 0;
    __syncthreads();
    sd[t] += x;
    __syncthreads();
  }
  if (t < nb) bsum[t] = sd[t] - v;
  if (t == 1023) row_ptr[n] = sd[1023];
}

__global__ void scan_add_kernel(int* __restrict__ excl, const int* __restrict__ bsum, int n) {
  int i = blockIdx.x * blockDim.x + threadIdx.x;
  if (i < n) excl[i] += bsum[i >> 10];
}

__global__ void fill_kernel(const int* __restrict__ src, const int* __restrict__ dst,
                            const int* __restrict__ row_ptr, int* __restrict__ cursor,
                            int* __restrict__ col, int E) {
  int i = blockIdx.x * blockDim.x + threadIdx.x;
  if (i < E) {
    int d = dst[i];
    int pos = row_ptr[d] + atomicAdd(&cursor[d], 1);
    col[pos] = src[i];
  }
}

// ---------- MFMA GEMM, register double-buffered ----------
// C[M,128] = A[M,K] @ Bt^T + bias; Bt: [128][K] bf16. No LDS (zero A reuse across
// blocks at N=128; Bt L2-resident). Wave: 64x64 via 4x4 of 16x16x32 MFMA.
// C/D layout: col=lane&15, row=quad*4+reg  [m89/m91].

__global__ __launch_bounds__(256) void gemm_mfma_kernel(
    const void* __restrict__ Ain, const __bf16* __restrict__ Bt,
    const float* __restrict__ bias, bf16* __restrict__ C,
    int M, int K, const float* __restrict__ rowscale, int do_relu,
    const int* __restrict__ flag, int a_dual) {
  int abf = a_dual ? flag[0] : 1;  // 1 => A is bf16
  int t = threadIdx.x;
  int wave = t >> 6, lane = t & 63;
  int l15 = lane & 15, quad = lane >> 4;
  int wm = wave >> 1, wn = wave & 1;
  int rowbase = blockIdx.x * 128 + wm * 64;
  int colbase = wn * 64;
  const __bf16* Ab = (const __bf16*)Ain;
  const float* Af = (const float*)Ain;

  f32x4 acc[4][4];
#pragma unroll
  for (int mt = 0; mt < 4; ++mt)
#pragma unroll
    for (int nt = 0; nt < 4; ++nt) acc[mt][nt] = (f32x4){0.f, 0.f, 0.f, 0.f};

  int arow[4];
#pragma unroll
  for (int mt = 0; mt < 4; ++mt) {
    int r = rowbase + mt * 16 + l15;
    arow[mt] = (r < M) ? r : (M - 1);  // clamp; garbage rows masked at store
  }
  int brow[4];
#pragma unroll
  for (int nt = 0; nt < 4; ++nt) brow[nt] = colbase + nt * 16 + l15;

  bf16x8 a[2][4], b[2][4];

  auto load_chunk = [&](int kc, bf16x8* av, bf16x8* bv) {
    int ko = kc + quad * 8;
    if (abf) {
#pragma unroll
      for (int mt = 0; mt < 4; ++mt)
        av[mt] = *(const bf16x8*)(Ab + (size_t)arow[mt] * K + ko);
    } else {
#pragma unroll
      for (int mt = 0; mt < 4; ++mt) {
        const float* p = Af + (size_t)arow[mt] * K + ko;
#pragma unroll
        for (int j = 0; j < 8; ++j) av[mt][j] = (__bf16)p[j];
      }
    }
#pragma unroll
    for (int nt = 0; nt < 4; ++nt)
      bv[nt] = *(const bf16x8*)(Bt + (size_t)brow[nt] * K + ko);
  };

  load_chunk(0, a[0], b[0]);
  int cur = 0;
  for (int kc = 0; kc < K; kc += 32) {
    int nxt = cur ^ 1;
    if (kc + 32 < K) load_chunk(kc + 32, a[nxt], b[nxt]);
#pragma unroll
    for (int mt = 0; mt < 4; ++mt)
#pragma unroll
      for (int nt = 0; nt < 4; ++nt)
        acc[mt][nt] = __builtin_amdgcn_mfma_f32_16x16x32_bf16(a[cur][mt], b[cur][nt], acc[mt][nt], 0, 0, 0);
    cur = nxt;
  }

#pragma unroll
  for (int mt = 0; mt < 4; ++mt) {
    int r0 = rowbase + mt * 16 + quad * 4;
#pragma unroll
    for (int nt = 0; nt < 4; ++nt) {
      int c = colbase + nt * 16 + l15;
      float bs = bias[c];
#pragma unroll
      for (int i = 0; i < 4; ++i) {
        int r = r0 + i;
        if (r < M) {
          float v = acc[mt][nt][i] + bs;
          if (rowscale) v *= rowscale[r];
          if (do_relu) v = fmaxf(v, 0.f);
          C[(size_t)r * 128 + c] = __float2bfloat16(v);
        }
      }
    }
  }
}

// ---------- gather: y[d] = relu(dinv[d]*(g[d] + sum_{s in CSR[d]} g[s])) ----------
// 8-wide unroll with branchless tail masking: 8 col loads + 8 g-row loads in
// flight per wave (round-3 profile: VGPR=8, 1 outstanding load, 1450 cyc/edge).

__global__ __launch_bounds__(256) void gather_kernel(
    const bf16* __restrict__ g, const int* __restrict__ row_ptr, const int* __restrict__ col,
    const float* __restrict__ dinv, bf16* __restrict__ y, int n) {
  int wave = threadIdx.x >> 6;
  int lane = threadIdx.x & 63;
  int node = blockIdx.x * 4 + wave;
  if (node >= n) return;
  const bf162* gp = (const bf162*)g;
  bf162 sv = gp[(size_t)node * 64 + lane];
  float ax = __bfloat162float(sv.x), ay = __bfloat162float(sv.y);
  float bx = 0.f, by = 0.f;
  int beg = row_ptr[node], end = row_ptr[node + 1];
  for (int e = beg; e < end; e += 8) {
    int s[8];
    float msk[8];
#pragma unroll
    for (int j = 0; j < 8; ++j) {
      int ee = e + j;
      bool ok = ee < end;
      s[j] = col[ok ? ee : e];  // e itself is always valid here
      msk[j] = ok ? 1.f : 0.f;
    }
    bf162 v[8];
#pragma unroll
    for (int j = 0; j < 8; ++j) v[j] = gp[(size_t)s[j] * 64 + lane];
#pragma unroll
    for (int j = 0; j < 8; j += 2) {
      ax = fmaf(msk[j], __bfloat162float(v[j].x), ax);
      ay = fmaf(msk[j], __bfloat162float(v[j].y), ay);
      bx = fmaf(msk[j + 1], __bfloat162float(v[j + 1].x), bx);
      by = fmaf(msk[j + 1], __bfloat162float(v[j + 1].y), by);
    }
  }
  float dv = dinv[node];
  float ox = fmaxf((ax + bx) * dv, 0.f);
  float oy = fmaxf((ay + by) * dv, 0.f);
  bf162 o;
  o.x = __float2bfloat16(ox);
  o.y = __float2bfloat16(oy);
  ((bf162*)y)[(size_t)node * 64 + lane] = o;
}

// ---------- fc3 (128->64) + log_softmax fused ----------

__global__ __launch_bounds__(256) void fc3_softmax_kernel(
    const bf16* __restrict__ y, const float* __restrict__ W, const float* __restrict__ b,
    void* __restrict__ out, int n, const int* __restrict__ flag) {
  __shared__ float Wl[128][64];
  __shared__ float bl[64];
  int isbf = flag[0];
  int t = threadIdx.x;
  for (int u = t; u < 128 * 64; u += 256) Wl[u >> 6][u & 63] = W[u];
  if (t < 64) bl[t] = b[t];
  __syncthreads();
  int wave = t >> 6, lane = t & 63;
  for (int r = blockIdx.x * 4 + wave; r < n; r += gridDim.x * 4) {
    const bf16* yr = y + (size_t)r * 128;
    float acc = bl[lane];
#pragma unroll 8
    for (int k = 0; k < 128; ++k) acc = fmaf(__bfloat162float(yr[k]), Wl[k][lane], acc);
    float m = acc;
#pragma unroll
    for (int off = 32; off > 0; off >>= 1) m = fmaxf(m, __shfl_xor(m, off, 64));
    float ex = __expf(acc - m);
#pragma unroll
    for (int off = 32; off > 0; off >>= 1) ex += __shfl_xor(ex, off, 64);
    float v = acc - m - __logf(ex);
    if (isbf)
      ((bf16*)out)[(size_t)r * 64 + lane] = __float2bfloat16(v);
    else
      ((float*)out)[(size_t)r * 64 + lane] = v;
  }
}

// ---------- launch ----------

extern "C" void kernel_launch(void* const* d_in, const int* in_sizes, int n_in,
                              void* d_out, int out_size, void* d_ws, size_t ws_size,
                              hipStream_t stream) {
  const void* x = d_in[0];
  const int* ei = (const int*)d_in[1];

  const int N = in_sizes[0] / 512;
  const int E = in_sizes[1] / 2;
  const int* srcp = ei;
  const int* dstp = ei + E;

  char* ws = (char*)d_ws;
  size_t off = 0;
  auto alloc = [&](size_t bytes) {
    void* p = ws + off;
    off = (off + bytes + 255) & ~(size_t)255;
    return p;
  };
  int*    flag    = (int*)alloc(4);
  int*    deg     = (int*)alloc((size_t)N * 4);
  int*    cursor  = (int*)alloc((size_t)N * 4);
  int*    row_ptr = (int*)alloc((size_t)(N + 1) * 4);
  int*    col     = (int*)alloc((size_t)E * 4);
  float*  dinv    = (float*)alloc((size_t)N * 4);
  int*    bsum    = (int*)alloc(1024 * 4);
  __bf16* W0t     = (__bf16*)alloc((size_t)512 * 128 * 2);
  __bf16* W1t     = (__bf16*)alloc((size_t)128 * 128 * 2);
  __bf16* W2t     = (__bf16*)alloc((size_t)128 * 128 * 2);
  __bf16* fc1t    = (__bf16*)alloc((size_t)128 * 128 * 2);
  __bf16* fc2t    = (__bf16*)alloc((size_t)128 * 128 * 2);
  float*  fc3wf   = (float*)alloc((size_t)128 * 64 * 4);
  float*  b0f     = (float*)alloc(128 * 4);
  float*  b1f     = (float*)alloc(128 * 4);
  float*  b2f     = (float*)alloc(128 * 4);
  float*  fc1bf   = (float*)alloc(128 * 4);
  float*  fc2bf   = (float*)alloc(128 * 4);
  float*  fc3bf   = (float*)alloc(64 * 4);
  bf16*   gbuf    = (bf16*)alloc((size_t)N * 128 * 2);
  bf16*   ybuf    = (bf16*)alloc((size_t)N * 128 * 2);

  const int tb = 256;

  detect_kernel<<<1, 64, 0, stream>>>((const unsigned short*)x, flag);

  CvtAll ca;
  ca.d[0]  = {d_in[2],  W0t,   512 * 128, 512, 128, 1};
  ca.d[1]  = {d_in[4],  W1t,   128 * 128, 128, 128, 1};
  ca.d[2]  = {d_in[6],  W2t,   128 * 128, 128, 128, 1};
  ca.d[3]  = {d_in[8],  fc1t,  128 * 128, 128, 128, 1};
  ca.d[4]  = {d_in[10], fc2t,  128 * 128, 128, 128, 1};
  ca.d[5]  = {d_in[3],  b0f,   128, 0, 0, 0};
  ca.d[6]  = {d_in[5],  b1f,   128, 0, 0, 0};
  ca.d[7]  = {d_in[7],  b2f,   128, 0, 0, 0};
  ca.d[8]  = {d_in[9],  fc1bf, 128, 0, 0, 0};
  ca.d[9]  = {d_in[11], fc2bf, 128, 0, 0, 0};
  ca.d[10] = {d_in[12], fc3wf, 128 * 64, 0, 0, 0};
  ca.d[11] = {d_in[13], fc3bf, 64, 0, 0, 0};
  convert_all_kernel<<<dim3(64, 12), 256, 0, stream>>>(ca, flag);

  hipMemsetAsync(deg, 0, (size_t)N * 4, stream);
  hipMemsetAsync(cursor, 0, (size_t)N * 4, stream);

  count_kernel<<<(E + tb - 1) / tb, tb, 0, stream>>>(dstp, deg, E);
  dinv_kernel<<<(N + tb - 1) / tb, tb, 0, stream>>>(deg, dinv, N);
  int nb = (N + 1023) / 1024;
  scan_block_kernel<<<nb, 1024, 0, stream>>>(deg, row_ptr, bsum, N);
  scan_sums_kernel<<<1, 1024, 0, stream>>>(bsum, nb, row_ptr, N);
  scan_add_kernel<<<(N + tb - 1) / tb, tb, 0, stream>>>(row_ptr, bsum, N);
  fill_kernel<<<(E + tb - 1) / tb, tb, 0, stream>>>(srcp, dstp, row_ptr, cursor, col, E);

  int gemm_blocks = (N + 127) / 128;
  int gat_blocks = (N + 3) / 4;

  // conv0
  gemm_mfma_kernel<<<gemm_blocks, 256, 0, stream>>>(x, W0t, b0f, gbuf, N, 512, dinv, 0, flag, 1);
  gather_kernel<<<gat_blocks, 256, 0, stream>>>(gbuf, row_ptr, col, dinv, ybuf, N);
  // conv1
  gemm_mfma_kernel<<<gemm_blocks, 256, 0, stream>>>(ybuf, W1t, b1f, gbuf, N, 128, dinv, 0, flag, 0);
  gather_kernel<<<gat_blocks, 256, 0, stream>>>(gbuf, row_ptr, col, dinv, ybuf, N);
  // conv2
  gemm_mfma_kernel<<<gemm_blocks, 256, 0, stream>>>(ybuf, W2t, b2f, gbuf, N, 128, dinv, 0, flag, 0);
  gather_kernel<<<gat_blocks, 256, 0, stream>>>(gbuf, row_ptr, col, dinv, ybuf, N);
  // fc1 (ybuf -> gbuf), fc2 (gbuf -> ybuf)
  gemm_mfma_kernel<<<gemm_blocks, 256, 0, stream>>>(ybuf, fc1t, fc1bf, gbuf, N, 128, nullptr, 1, flag, 0);
  gemm_mfma_kernel<<<gemm_blocks, 256, 0, stream>>>(gbuf, fc2t, fc2bf, ybuf, N, 128, nullptr, 1, flag, 0);
  // fc3 + log_softmax
  fc3_softmax_kernel<<<gat_blocks, 256, 0, stream>>>(ybuf, fc3wf, fc3bf, d_out, N, flag);
}

// Round 5
// 986.334 us; speedup vs baseline: 6.6082x; 6.6082x over previous
//
#include <hip/hip_runtime.h>
#include <hip/hip_bf16.h>
#include <cstdint>

typedef __hip_bfloat16 bf16;
typedef __hip_bfloat162 bf162;
typedef __bf16 bf16x8 __attribute__((ext_vector_type(8)));
typedef float f32x4 __attribute__((ext_vector_type(4)));

// ---------- dtype detection ----------
__global__ void detect_kernel(const unsigned short* __restrict__ xr, int* __restrict__ flag) {
  if (threadIdx.x == 0 && blockIdx.x == 0) {
    int pass = 0;
    for (int i = 0; i < 64; ++i) {
      unsigned short h = xr[2 * i];
      int e = (h >> 7) & 0xFF;
      if (e >= 110 && e <= 140) pass++;
    }
    *flag = (pass >= 32) ? 1 : 0;
  }
}

// ---------- batched weight conversion: 12 tensors in one launch ----------
struct CvtDesc {
  const void* src;
  void* dst;
  int n, fi, fo, mode;  // mode 1: transpose [fi][fo] -> bf16 [fo][fi]; mode 0: flat fp32
};
struct CvtAll { CvtDesc d[12]; };

__global__ void convert_all_kernel(CvtAll all, const int* __restrict__ flag) {
  CvtDesc dd = all.d[blockIdx.y];
  int isbf = *flag;
  for (int i = blockIdx.x * blockDim.x + threadIdx.x; i < dd.n; i += gridDim.x * blockDim.x) {
    float v = isbf ? __bfloat162float(((const bf16*)dd.src)[i]) : ((const float*)dd.src)[i];
    if (dd.mode) {
      int k = i / dd.fo, nn = i - k * dd.fo;
      ((__bf16*)dd.dst)[(size_t)nn * dd.fi + k] = (__bf16)v;
    } else {
      ((float*)dd.dst)[i] = v;
    }
  }
}

// ---------- graph preprocessing ----------

__global__ void count_kernel(const int* __restrict__ dst, int* __restrict__ deg, int E) {
  int i = blockIdx.x * blockDim.x + threadIdx.x;
  if (i < E) atomicAdd(&deg[dst[i]], 1);
}

__global__ void dinv_kernel(const int* __restrict__ deg, float* __restrict__ dinv, int n) {
  int i = blockIdx.x * blockDim.x + threadIdx.x;
  if (i < n) dinv[i] = rsqrtf((float)(deg[i] + 1));  // +1 self-loop
}

__global__ void scan_block_kernel(const int* __restrict__ counts, int* __restrict__ excl,
                                  int* __restrict__ bsum, int n) {
  __shared__ int sd[1024];
  int t = threadIdx.x;
  int i = blockIdx.x * 1024 + t;
  int v = (i < n) ? counts[i] : 0;
  sd[t] = v;
  __syncthreads();
  for (int off = 1; off < 1024; off <<= 1) {
    int x = (t >= off) ? sd[t - off] : 0;
    __syncthreads();
    sd[t] += x;
    __syncthreads();
  }
  if (i < n) excl[i] = sd[t] - v;
  if (t == 1023) bsum[blockIdx.x] = sd[1023];
}

__global__ void scan_sums_kernel(int* __restrict__ bsum, int nb, int* __restrict__ row_ptr, int n) {
  __shared__ int sd[1024];
  int t = threadIdx.x;
  int v = (t < nb) ? bsum[t] : 0;
  sd[t] = v;
  __syncthreads();
  for (int off = 1; off < 1024; off <<= 1) {
    int x = (t >= off) ? sd[t - off] : 0;
    __syncthreads();
    sd[t] += x;
    __syncthreads();
  }
  if (t < nb) bsum[t] = sd[t] - v;
  if (t == 1023) row_ptr[n] = sd[1023];
}

__global__ void scan_add_kernel(int* __restrict__ excl, const int* __restrict__ bsum, int n) {
  int i = blockIdx.x * blockDim.x + threadIdx.x;
  if (i < n) excl[i] += bsum[i >> 10];
}

__global__ void fill_kernel(const int* __restrict__ src, const int* __restrict__ dst,
                            const int* __restrict__ row_ptr, int* __restrict__ cursor,
                            int* __restrict__ col, int E) {
  int i = blockIdx.x * blockDim.x + threadIdx.x;
  if (i < E) {
    int d = dst[i];
    int pos = row_ptr[d] + atomicAdd(&cursor[d], 1);
    col[pos] = src[i];
  }
}

// ---------- MFMA GEMM, register double-buffered with STATIC indices ----------
// C[M,128] = A[M,K] @ Bt^T + bias; Bt: [128][K] bf16. No LDS (zero A reuse across
// blocks at N=128; Bt L2-resident). Wave: 64x64 via 4x4 of 16x16x32 MFMA.
// C/D layout: col=lane&15, row=quad*4+reg  [m89/m91].
// Round-4 lesson: runtime-indexed fragment arrays (a[cur][..]) get demoted to
// scratch -> MfmaUtil 0.17%, 3.1 ms. All buffer selection is compile-time here.

template <int K, int ADUAL>
__global__ __launch_bounds__(256) void gemm_mfma_kernel(
    const void* __restrict__ Ain, const __bf16* __restrict__ Bt,
    const float* __restrict__ bias, bf16* __restrict__ C,
    int M, const float* __restrict__ rowscale, int do_relu,
    const int* __restrict__ flag) {
  const int abf = ADUAL ? flag[0] : 1;  // 1 => A is bf16
  int t = threadIdx.x;
  int wave = t >> 6, lane = t & 63;
  int l15 = lane & 15, quad = lane >> 4;
  int wm = wave >> 1, wn = wave & 1;
  int rowbase = blockIdx.x * 128 + wm * 64;
  int colbase = wn * 64;
  const __bf16* Ab = (const __bf16*)Ain;
  const float* Af = (const float*)Ain;

  f32x4 acc[4][4];
#pragma unroll
  for (int mt = 0; mt < 4; ++mt)
#pragma unroll
    for (int nt = 0; nt < 4; ++nt) acc[mt][nt] = (f32x4){0.f, 0.f, 0.f, 0.f};

  int arow[4];
#pragma unroll
  for (int mt = 0; mt < 4; ++mt) {
    int r = rowbase + mt * 16 + l15;
    arow[mt] = (r < M) ? r : (M - 1);  // clamp; garbage rows masked at store
  }
  int brow[4];
#pragma unroll
  for (int nt = 0; nt < 4; ++nt) brow[nt] = colbase + nt * 16 + l15;

  bf16x8 aA[4], bA[4], aB[4], bB[4];

  auto load_chunk = [&](int kc, bf16x8 (&av)[4], bf16x8 (&bv)[4]) {
    int ko = kc + quad * 8;
    if (abf) {
#pragma unroll
      for (int mt = 0; mt < 4; ++mt)
        av[mt] = *(const bf16x8*)(Ab + (size_t)arow[mt] * K + ko);
    } else {
#pragma unroll
      for (int mt = 0; mt < 4; ++mt) {
        const float* p = Af + (size_t)arow[mt] * K + ko;
#pragma unroll
        for (int j = 0; j < 8; ++j) av[mt][j] = (__bf16)p[j];
      }
    }
#pragma unroll
    for (int nt = 0; nt < 4; ++nt)
      bv[nt] = *(const bf16x8*)(Bt + (size_t)brow[nt] * K + ko);
  };

  auto mfma16 = [&](const bf16x8 (&av)[4], const bf16x8 (&bv)[4]) {
#pragma unroll
    for (int mt = 0; mt < 4; ++mt)
#pragma unroll
      for (int nt = 0; nt < 4; ++nt)
        acc[mt][nt] =
            __builtin_amdgcn_mfma_f32_16x16x32_bf16(av[mt], bv[nt], acc[mt][nt], 0, 0, 0);
  };

  constexpr int NC = K / 32;  // 16 (K=512) or 4 (K=128); always even
  load_chunk(0, aA, bA);
#pragma unroll
  for (int c = 0; c < NC; c += 2) {
    if (c + 1 < NC) load_chunk((c + 1) * 32, aB, bB);
    mfma16(aA, bA);
    if (c + 2 < NC) load_chunk((c + 2) * 32, aA, bA);
    if (c + 1 < NC) mfma16(aB, bB);
  }

#pragma unroll
  for (int mt = 0; mt < 4; ++mt) {
    int r0 = rowbase + mt * 16 + quad * 4;
#pragma unroll
    for (int nt = 0; nt < 4; ++nt) {
      int c = colbase + nt * 16 + l15;
      float bs = bias[c];
#pragma unroll
      for (int i = 0; i < 4; ++i) {
        int r = r0 + i;
        if (r < M) {
          float v = acc[mt][nt][i] + bs;
          if (rowscale) v *= rowscale[r];
          if (do_relu) v = fmaxf(v, 0.f);
          C[(size_t)r * 128 + c] = __float2bfloat16(v);
        }
      }
    }
  }
}

// ---------- gather: y[d] = relu(dinv[d]*(g[d] + sum_{s in CSR[d]} g[s])) ----------
// 8-wide unroll with branchless tail masking: 8 col loads + 8 g-row loads in
// flight per wave (round-3 profile: VGPR=8, 1 outstanding load, ~1450 cyc/edge).

__global__ __launch_bounds__(256) void gather_kernel(
    const bf16* __restrict__ g, const int* __restrict__ row_ptr, const int* __restrict__ col,
    const float* __restrict__ dinv, bf16* __restrict__ y, int n) {
  int wave = threadIdx.x >> 6;
  int lane = threadIdx.x & 63;
  int node = blockIdx.x * 4 + wave;
  if (node >= n) return;
  const bf162* gp = (const bf162*)g;
  bf162 sv = gp[(size_t)node * 64 + lane];
  float ax = __bfloat162float(sv.x), ay = __bfloat162float(sv.y);
  float bx = 0.f, by = 0.f;
  int beg = row_ptr[node], end = row_ptr[node + 1];
  for (int e = beg; e < end; e += 8) {
    int s[8];
    float msk[8];
#pragma unroll
    for (int j = 0; j < 8; ++j) {
      int ee = e + j;
      bool ok = ee < end;
      s[j] = col[ok ? ee : e];  // e itself is always valid here
      msk[j] = ok ? 1.f : 0.f;
    }
    bf162 v[8];
#pragma unroll
    for (int j = 0; j < 8; ++j) v[j] = gp[(size_t)s[j] * 64 + lane];
#pragma unroll
    for (int j = 0; j < 8; j += 2) {
      ax = fmaf(msk[j], __bfloat162float(v[j].x), ax);
      ay = fmaf(msk[j], __bfloat162float(v[j].y), ay);
      bx = fmaf(msk[j + 1], __bfloat162float(v[j + 1].x), bx);
      by = fmaf(msk[j + 1], __bfloat162float(v[j + 1].y), by);
    }
  }
  float dv = dinv[node];
  float ox = fmaxf((ax + bx) * dv, 0.f);
  float oy = fmaxf((ay + by) * dv, 0.f);
  bf162 o;
  o.x = __float2bfloat16(ox);
  o.y = __float2bfloat16(oy);
  ((bf162*)y)[(size_t)node * 64 + lane] = o;
}

// ---------- fc3 (128->64) + log_softmax fused ----------

__global__ __launch_bounds__(256) void fc3_softmax_kernel(
    const bf16* __restrict__ y, const float* __restrict__ W, const float* __restrict__ b,
    void* __restrict__ out, int n, const int* __restrict__ flag) {
  __shared__ float Wl[128][64];
  __shared__ float bl[64];
  int isbf = flag[0];
  int t = threadIdx.x;
  for (int u = t; u < 128 * 64; u += 256) Wl[u >> 6][u & 63] = W[u];
  if (t < 64) bl[t] = b[t];
  __syncthreads();
  int wave = t >> 6, lane = t & 63;
  for (int r = blockIdx.x * 4 + wave; r < n; r += gridDim.x * 4) {
    const bf16* yr = y + (size_t)r * 128;
    float acc = bl[lane];
#pragma unroll 8
    for (int k = 0; k < 128; ++k) acc = fmaf(__bfloat162float(yr[k]), Wl[k][lane], acc);
    float m = acc;
#pragma unroll
    for (int off = 32; off > 0; off >>= 1) m = fmaxf(m, __shfl_xor(m, off, 64));
    float ex = __expf(acc - m);
#pragma unroll
    for (int off = 32; off > 0; off >>= 1) ex += __shfl_xor(ex, off, 64);
    float v = acc - m - __logf(ex);
    if (isbf)
      ((bf16*)out)[(size_t)r * 64 + lane] = __float2bfloat16(v);
    else
      ((float*)out)[(size_t)r * 64 + lane] = v;
  }
}

// ---------- launch ----------

extern "C" void kernel_launch(void* const* d_in, const int* in_sizes, int n_in,
                              void* d_out, int out_size, void* d_ws, size_t ws_size,
                              hipStream_t stream) {
  const void* x = d_in[0];
  const int* ei = (const int*)d_in[1];

  const int N = in_sizes[0] / 512;
  const int E = in_sizes[1] / 2;
  const int* srcp = ei;
  const int* dstp = ei + E;

  char* ws = (char*)d_ws;
  size_t off = 0;
  auto alloc = [&](size_t bytes) {
    void* p = ws + off;
    off = (off + bytes + 255) & ~(size_t)255;
    return p;
  };
  int*    flag    = (int*)alloc(4);
  int*    deg     = (int*)alloc((size_t)N * 4);
  int*    cursor  = (int*)alloc((size_t)N * 4);
  int*    row_ptr = (int*)alloc((size_t)(N + 1) * 4);
  int*    col     = (int*)alloc((size_t)E * 4);
  float*  dinv    = (float*)alloc((size_t)N * 4);
  int*    bsum    = (int*)alloc(1024 * 4);
  __bf16* W0t     = (__bf16*)alloc((size_t)512 * 128 * 2);
  __bf16* W1t     = (__bf16*)alloc((size_t)128 * 128 * 2);
  __bf16* W2t     = (__bf16*)alloc((size_t)128 * 128 * 2);
  __bf16* fc1t    = (__bf16*)alloc((size_t)128 * 128 * 2);
  __bf16* fc2t    = (__bf16*)alloc((size_t)128 * 128 * 2);
  float*  fc3wf   = (float*)alloc((size_t)128 * 64 * 4);
  float*  b0f     = (float*)alloc(128 * 4);
  float*  b1f     = (float*)alloc(128 * 4);
  float*  b2f     = (float*)alloc(128 * 4);
  float*  fc1bf   = (float*)alloc(128 * 4);
  float*  fc2bf   = (float*)alloc(128 * 4);
  float*  fc3bf   = (float*)alloc(64 * 4);
  bf16*   gbuf    = (bf16*)alloc((size_t)N * 128 * 2);
  bf16*   ybuf    = (bf16*)alloc((size_t)N * 128 * 2);

  const int tb = 256;

  detect_kernel<<<1, 64, 0, stream>>>((const unsigned short*)x, flag);

  CvtAll ca;
  ca.d[0]  = {d_in[2],  W0t,   512 * 128, 512, 128, 1};
  ca.d[1]  = {d_in[4],  W1t,   128 * 128, 128, 128, 1};
  ca.d[2]  = {d_in[6],  W2t,   128 * 128, 128, 128, 1};
  ca.d[3]  = {d_in[8],  fc1t,  128 * 128, 128, 128, 1};
  ca.d[4]  = {d_in[10], fc2t,  128 * 128, 128, 128, 1};
  ca.d[5]  = {d_in[3],  b0f,   128, 0, 0, 0};
  ca.d[6]  = {d_in[5],  b1f,   128, 0, 0, 0};
  ca.d[7]  = {d_in[7],  b2f,   128, 0, 0, 0};
  ca.d[8]  = {d_in[9],  fc1bf, 128, 0, 0, 0};
  ca.d[9]  = {d_in[11], fc2bf, 128, 0, 0, 0};
  ca.d[10] = {d_in[12], fc3wf, 128 * 64, 0, 0, 0};
  ca.d[11] = {d_in[13], fc3bf, 64, 0, 0, 0};
  convert_all_kernel<<<dim3(64, 12), 256, 0, stream>>>(ca, flag);

  hipMemsetAsync(deg, 0, (size_t)N * 4, stream);
  hipMemsetAsync(cursor, 0, (size_t)N * 4, stream);

  count_kernel<<<(E + tb - 1) / tb, tb, 0, stream>>>(dstp, deg, E);
  dinv_kernel<<<(N + tb - 1) / tb, tb, 0, stream>>>(deg, dinv, N);
  int nb = (N + 1023) / 1024;
  scan_block_kernel<<<nb, 1024, 0, stream>>>(deg, row_ptr, bsum, N);
  scan_sums_kernel<<<1, 1024, 0, stream>>>(bsum, nb, row_ptr, N);
  scan_add_kernel<<<(N + tb - 1) / tb, tb, 0, stream>>>(row_ptr, bsum, N);
  fill_kernel<<<(E + tb - 1) / tb, tb, 0, stream>>>(srcp, dstp, row_ptr, cursor, col, E);

  int gemm_blocks = (N + 127) / 128;
  int gat_blocks = (N + 3) / 4;

  // conv0
  gemm_mfma_kernel<512, 1><<<gemm_blocks, 256, 0, stream>>>(x, W0t, b0f, gbuf, N, dinv, 0, flag);
  gather_kernel<<<gat_blocks, 256, 0, stream>>>(gbuf, row_ptr, col, dinv, ybuf, N);
  // conv1
  gemm_mfma_kernel<128, 0><<<gemm_blocks, 256, 0, stream>>>(ybuf, W1t, b1f, gbuf, N, dinv, 0, flag);
  gather_kernel<<<gat_blocks, 256, 0, stream>>>(gbuf, row_ptr, col, dinv, ybuf, N);
  // conv2
  gemm_mfma_kernel<128, 0><<<gemm_blocks, 256, 0, stream>>>(ybuf, W2t, b2f, gbuf, N, dinv, 0, flag);
  gather_kernel<<<gat_blocks, 256, 0, stream>>>(gbuf, row_ptr, col, dinv, ybuf, N);
  // fc1 (ybuf -> gbuf), fc2 (gbuf -> ybuf)
  gemm_mfma_kernel<128, 0><<<gemm_blocks, 256, 0, stream>>>(ybuf, fc1t, fc1bf, gbuf, N, nullptr, 1, flag);
  gemm_mfma_kernel<128, 0><<<gemm_blocks, 256, 0, stream>>>(gbuf, fc2t, fc2bf, ybuf, N, nullptr, 1, flag);
  // fc3 + log_softmax
  fc3_softmax_kernel<<<gat_blocks, 256, 0, stream>>>(ybuf, fc3wf, fc3bf, d_out, N, flag);
}